// Round 10
// baseline (273.972 us; speedup 1.0000x reference)
//
#include <hip/hip_runtime.h>
#include <hip/hip_bf16.h>

#define TT 16      // in_length
#define EE 32      // embedding size
#define HH 64      // encoder size
#define NGRP 32    // vehicles per group
#define CC 3       // classes

typedef __attribute__((ext_vector_type(8))) short short8;
typedef __attribute__((ext_vector_type(4))) short short4v;
typedef __attribute__((ext_vector_type(4))) float floatx4;

#define MFMA16(a, b, c) __builtin_amdgcn_mfma_f32_16x16x32_bf16((a), (b), (c), 0, 0, 0)

#define RLN2 1.4426950408889634f   // 1/ln2

__device__ __forceinline__ float leakyf(float x) { return fmaxf(x, 0.1f * x); }
__device__ __forceinline__ short f2bf(float x) {   // fp32 -> bf16 RNE (one-time weights)
    unsigned u = __float_as_uint(x);
    return (short)((u + 0x7FFFu + ((u >> 16) & 1u)) >> 16);
}
__device__ __forceinline__ short f2bf_h(float x) { // fp32 -> bf16 round-half-up (per-step)
    return (short)((__float_as_uint(x) + 0x8000u) >> 16);
}
__device__ __forceinline__ float bf2f(short s) {
    return __uint_as_float(((unsigned)(unsigned short)s) << 16);
}
__device__ __forceinline__ short8 ld8bf(const float* __restrict__ p) {
    const float4 a = *(const float4*)p;
    const float4 b = *(const float4*)(p + 4);
    short8 v;
    v[0] = f2bf(a.x); v[1] = f2bf(a.y); v[2] = f2bf(a.z); v[3] = f2bf(a.w);
    v[4] = f2bf(b.x); v[5] = f2bf(b.y); v[6] = f2bf(b.z); v[7] = f2bf(b.w);
    return v;
}
__device__ __forceinline__ short8 ld8bfs(const float* __restrict__ p, float s) {
    const float4 a = *(const float4*)p;
    const float4 b = *(const float4*)(p + 4);
    short8 v;
    v[0] = f2bf(a.x * s); v[1] = f2bf(a.y * s); v[2] = f2bf(a.z * s); v[3] = f2bf(a.w * s);
    v[4] = f2bf(b.x * s); v[5] = f2bf(b.y * s); v[6] = f2bf(b.z * s); v[7] = f2bf(b.w * s);
    return v;
}

// ---------------------------------------------------------------------------
// Kernel 1: ONE GRU DIRECTION per block. Grid 2*G; block 256 thr = 4 waves.
//   g = bx>>1, dir = bx&1. Wave wd owns hidden dims [16wd,16wd+16).
//   Barrier spans only 4 waves; 6 blocks/CU (LDS 16.4 KB, launch_bounds(256,6)
//   VGPR cap 85 > measured 64 need) -> ~6 independent barrier groups per CU.
//   One barrier/step: Hf double-buffered (8 KB), X regenerated per step into
//   double-buffered Xb (4 KB) by all 256 threads from LDS-staged scene.
//   B-frags pre-scaled -1/ln2 (r,z) / 2/ln2 (n); scalar biases post-MFMA
//   (floatx4 C-inits spill — R5/R7); gates via raw exp2+rcp.
//   Final h written to d_ws frag-packed bf16: hws[bx][2048 shorts] (8 MB tot).
//   A-frag: A[m][k]: slot=((k&31)>>3)*16+m, elem k&7, ks=k>>5
//   B-frag: B[k=(lane>>4)*8+i][n=lane&15]
//   C/D   : row=(lane>>4)*4+reg, col=lane&15
// ---------------------------------------------------------------------------
__global__ __launch_bounds__(256, 6) void gru_dir_kernel(
    const float* __restrict__ scene, const int* __restrict__ index_div,
    const float* __restrict__ W_emb, const float* __restrict__ b_emb,
    const float* __restrict__ Wih_f, const float* __restrict__ Whh_f,
    const float* __restrict__ bih_f, const float* __restrict__ bhh_f,
    const float* __restrict__ Wih_b, const float* __restrict__ Whh_b,
    const float* __restrict__ bih_b, const float* __restrict__ bhh_b,
    short* __restrict__ hws)
{
    __shared__ float sscene[32][33];             // [c][veh] 4224 B
    __shared__ __align__(16) short Hf[2 * 2 * 2 * 64 * 8];  // [buf][ks][mt][slot][8] 8 KB
    __shared__ __align__(16) short Xb[2 * 2 * 64 * 8];      // [buf][mt][lane][8]     4 KB

    const int bx   = blockIdx.x;
    const int g    = bx >> 1;
    const int dir  = bx & 1;
    const int tid  = threadIdx.x;
    const int lane = tid & 63;
    const int wd   = __builtin_amdgcn_readfirstlane(tid >> 6);  // 0..3
    const int cc   = lane & 15;
    const int quad = lane >> 4;
    const int j    = wd * 16 + cc;            // hidden dim / gate column
    const int ks_w = j >> 5;
    const int qa_w = (j >> 3) & 3;
    const int ii_w = j & 7;

    // ---- stage gathered scene rows into sscene[c][veh] ----
    #pragma unroll
    for (int rep = 0; rep < 4; ++rep) {
        const int idx = tid + rep * 256;
        const int v = idx >> 5, c = idx & 31;
        const int n = index_div[g * NGRP + v];
        sscene[c][v] = scene[n * 32 + c];
    }

    // ---- per-wave B-frags (this block's dir), pre-scaled; scalar biases ----
    const float* Wih = dir ? Wih_b : Wih_f;
    const float* Whh = dir ? Whh_b : Whh_f;
    const float* bih = dir ? bih_b : bih_f;
    const float* bhh = dir ? bhh_b : bhh_f;
    const int k0 = quad * 8;
    const float SRZ = -RLN2, SN = 2.0f * RLN2;
    const short8 Br0  = ld8bfs(Whh + (j      ) * 64 + k0,      SRZ);
    const short8 Br1  = ld8bfs(Whh + (j      ) * 64 + 32 + k0, SRZ);
    const short8 Br2  = ld8bfs(Wih + (j      ) * 32 + k0,      SRZ);
    const short8 Bz0  = ld8bfs(Whh + (j +  64) * 64 + k0,      SRZ);
    const short8 Bz1  = ld8bfs(Whh + (j +  64) * 64 + 32 + k0, SRZ);
    const short8 Bz2  = ld8bfs(Wih + (j +  64) * 32 + k0,      SRZ);
    const short8 Bhn0 = ld8bfs(Whh + (j + 128) * 64 + k0,      SN);
    const short8 Bhn1 = ld8bfs(Whh + (j + 128) * 64 + 32 + k0, SN);
    const short8 Bxn  = ld8bfs(Wih + (j + 128) * 32 + k0,      SN);
    const float vb_r  = SRZ * (bih[j] + bhh[j]);
    const float vb_z  = SRZ * (bih[j + 64] + bhh[j + 64]);
    const float vb_xn = SN * bih[j + 128];
    const float vb_hn = SN * bhh[j + 128];

    // ---- per-thread emb generator (256 threads; weights in 12 regs) ----
    const int veh_x = tid & 31;
    const int q2    = tid >> 5;               // 0..7
    const int e0    = q2 * 4;
    float w0e[4], w1e[4], bbe[4];
    #pragma unroll
    for (int d = 0; d < 4; ++d) {
        w0e[d] = W_emb[e0 + d];
        w1e[d] = W_emb[EE + e0 + d];
        bbe[d] = b_emb[e0 + d];
    }
    // X-frag: [mt=veh>>4][slot=(e>>3)*16+(veh&15)] elem e&7
    const int xoff = ((veh_x >> 4) * 64 + (q2 >> 1) * 16 + (veh_x & 15)) * 8
                   + (q2 & 1) * 4;            // + buf*1024

    __syncthreads();   // sscene ready

    // ---- zero Hf buf0 + prefill Xb buf0 for step 0 ----
    {
        const short8 z8 = {0, 0, 0, 0, 0, 0, 0, 0};
        *(short8*)&Hf[tid * 8] = z8;          // 256 x 16B = buf0
        const int t0 = dir ? (TT - 1) : 0;
        const float xs = sscene[t0][veh_x];
        const float ys = sscene[16 + t0][veh_x];
        short4v v;
        #pragma unroll
        for (int d = 0; d < 4; ++d)
            v[d] = f2bf_h(leakyf(fmaf(xs, w0e[d], fmaf(ys, w1e[d], bbe[d]))));
        *(short4v*)&Xb[xoff] = v;
    }

    float h_reg[8];
    #pragma unroll
    for (int i = 0; i < 8; ++i) h_reg[i] = 0.0f;

    __syncthreads();

    // ---- GRU main loop: ONE barrier per step ----
    #pragma unroll 2
    for (int s = 0; s < TT; ++s) {
        const int pb = s & 1, nb = pb ^ 1;
        const short* HfD = &Hf[pb * 2048];
        short*       HfN = &Hf[nb * 2048];
        const short* XbD = &Xb[pb * 1024];
        #pragma unroll
        for (int mt = 0; mt < 2; ++mt) {
            const short8 Ah0 = *(const short8*)&HfD[((0 * 2 + mt) * 64 + lane) * 8];
            const short8 Ah1 = *(const short8*)&HfD[((1 * 2 + mt) * 64 + lane) * 8];
            const short8 Axx = *(const short8*)&XbD[(mt * 64 + lane) * 8];
            const floatx4 z4 = {0.f, 0.f, 0.f, 0.f};
            const floatx4 ar  = MFMA16(Axx, Br2, MFMA16(Ah1, Br1, MFMA16(Ah0, Br0, z4)));
            const floatx4 az  = MFMA16(Axx, Bz2, MFMA16(Ah1, Bz1, MFMA16(Ah0, Bz0, z4)));
            const floatx4 ahn = MFMA16(Ah1, Bhn1, MFMA16(Ah0, Bhn0, z4));
            const floatx4 axn = MFMA16(Axx, Bxn, z4);
            #pragma unroll
            for (int r = 0; r < 4; ++r) {
                const float rr = __builtin_amdgcn_rcpf(1.0f + __builtin_amdgcn_exp2f(ar[r] + vb_r));
                const float zz = __builtin_amdgcn_rcpf(1.0f + __builtin_amdgcn_exp2f(az[r] + vb_z));
                const float y  = fmaf(rr, ahn[r] + vb_hn, axn[r] + vb_xn);
                const float ng = fmaf(-2.0f,
                                      __builtin_amdgcn_rcpf(__builtin_amdgcn_exp2f(y) + 1.0f),
                                      1.0f);
                const float h0 = h_reg[mt * 4 + r];
                h_reg[mt * 4 + r] = fmaf(zz, h0 - ng, ng);  // (1-z)*ng + z*h
            }
        }
        // write new h into buf nb (natural A-frag slots); regen X for s+1
        #pragma unroll
        for (int mt = 0; mt < 2; ++mt) {
            #pragma unroll
            for (int r = 0; r < 4; ++r) {
                const int slot = qa_w * 16 + quad * 4 + r;
                HfN[((ks_w * 2 + mt) * 64 + slot) * 8 + ii_w] = f2bf_h(h_reg[mt * 4 + r]);
            }
        }
        if (s + 1 < TT) {
            const int tn = dir ? (TT - 2 - s) : (s + 1);
            const float xs = sscene[tn][veh_x];
            const float ys = sscene[16 + tn][veh_x];
            short4v v;
            #pragma unroll
            for (int d = 0; d < 4; ++d)
                v[d] = f2bf_h(leakyf(fmaf(xs, w0e[d], fmaf(ys, w1e[d], bbe[d]))));
            *(short4v*)&Xb[xoff + nb * 1024] = v;
        }
        __syncthreads();
    }
    // Final h in Hf buf0 (s=15 wrote nb=0). Copy frag-packed to workspace.
    *(short8*)&hws[(size_t)bx * 2048 + tid * 8] = *(const short8*)&Hf[tid * 8];
}

// ---------------------------------------------------------------------------
// Kernel 2: seq_enc epilogue (MFMA, reads h frags from ws) + spatial pairwise
// MLP (MFMA) + head. One block per group, 256 thr = 4 waves.
// ---------------------------------------------------------------------------
__global__ __launch_bounds__(256, 4) void tail_kernel(
    const float* __restrict__ scene, const int* __restrict__ index_div,
    const short* __restrict__ hws,
    const float* __restrict__ Wm, const float* __restrict__ bm,
    const float* __restrict__ Ws1, const float* __restrict__ bs1,
    const float* __restrict__ Ws2, const float* __restrict__ bs2,
    const float* __restrict__ Wo1, const float* __restrict__ bo1,
    const float* __restrict__ Wo2, const float* __restrict__ bo2,
    float* __restrict__ full_enc, float* __restrict__ out)
{
    __shared__ float sscene[32][33];   // 4.2 KB
    __shared__ float su[NGRP][68];     // 8.7 KB
    __shared__ float fe[NGRP][68];     // 8.7 KB (cols 0..63 used)
    __shared__ float swo1[1024];       // 4 KB
    __shared__ float szero[32];

    const int g    = blockIdx.x;
    const int tid  = threadIdx.x;
    const int lane = tid & 63;
    const int w    = __builtin_amdgcn_readfirstlane(tid >> 6);  // 0..3
    const int cc   = lane & 15;
    const int quad = lane >> 4;

    // ---- stage sscene[c][veh], swo1, szero ----
    #pragma unroll
    for (int rep = 0; rep < 4; ++rep) {
        const int idx = tid + rep * 256;
        const int v = idx >> 5, c = idx & 31;
        const int n = index_div[g * NGRP + v];
        sscene[c][v] = scene[n * 32 + c];
    }
    *(float4*)&swo1[tid * 4] = *(const float4*)&Wo1[tid * 4];
    if (tid < 32) {
        float zs = bs2[tid];
        #pragma unroll
        for (int d = 0; d < HH; ++d) zs = fmaf(leakyf(bs1[d]), Ws2[d * 32 + tid], zs);
        szero[tid] = leakyf(zs);
    }
    __syncthreads();

    // ---- su = feat @ Ws1 ----
    {
        const int v  = tid >> 3;
        const int d0 = (tid & 7) * 8;
        float acc[8];
        #pragma unroll
        for (int i = 0; i < 8; ++i) acc[i] = 0.0f;
        #pragma unroll
        for (int e = 0; e < EE; ++e) {
            const float f = sscene[e][v];
            const float4 w0 = *(const float4*)&Ws1[e * 64 + d0];
            const float4 w1 = *(const float4*)&Ws1[e * 64 + d0 + 4];
            acc[0] = fmaf(f, w0.x, acc[0]); acc[1] = fmaf(f, w0.y, acc[1]);
            acc[2] = fmaf(f, w0.z, acc[2]); acc[3] = fmaf(f, w0.w, acc[3]);
            acc[4] = fmaf(f, w1.x, acc[4]); acc[5] = fmaf(f, w1.y, acc[5]);
            acc[6] = fmaf(f, w1.z, acc[6]); acc[7] = fmaf(f, w1.w, acc[7]);
        }
        #pragma unroll
        for (int i = 0; i < 8; ++i) su[v][d0 + i] = acc[i];
    }

    // ---- seq_enc epilogue: hm = 0.5*(h_f+h_b) as A-frags from ws, MFMA ----
    {
        const int nt   = w >> 1;
        const int mt_e = w & 1;
        const int n_col = nt * 16 + cc;
        short8 Bm0, Bm1;
        #pragma unroll
        for (int i = 0; i < 8; ++i) {
            Bm0[i] = f2bf(Wm[(     quad * 8 + i) * 32 + n_col]);
            Bm1[i] = f2bf(Wm[(32 + quad * 8 + i) * 32 + n_col]);
        }
        short8 A0, A1;
        #pragma unroll
        for (int ks = 0; ks < 2; ++ks) {
            const short8 F = *(const short8*)&hws[(size_t)(g * 2 + 0) * 2048 + ((ks * 2 + mt_e) * 64 + lane) * 8];
            const short8 B = *(const short8*)&hws[(size_t)(g * 2 + 1) * 2048 + ((ks * 2 + mt_e) * 64 + lane) * 8];
            #pragma unroll
            for (int i = 0; i < 8; ++i) {
                const short v = f2bf(0.5f * (bf2f(F[i]) + bf2f(B[i])));
                if (ks == 0) A0[i] = v; else A1[i] = v;
            }
        }
        const floatx4 z4 = {0.f, 0.f, 0.f, 0.f};
        const floatx4 acc = MFMA16(A1, Bm1, MFMA16(A0, Bm0, z4));
        const float bmn = bm[n_col];
        #pragma unroll
        for (int r = 0; r < 4; ++r) {
            const int veh = mt_e * 16 + quad * 4 + r;
            const float sv = leakyf(acc[r] + bmn);
            const int n = index_div[g * NGRP + veh];
            full_enc[n * HH + n_col] = sv;
            fe[veh][n_col] = sv;
        }
    }

    // ---- spatial B-frags ----
    short8 Bw00, Bw01, Bw10, Bw11;
    #pragma unroll
    for (int i = 0; i < 8; ++i) {
        Bw00[i] = f2bf(Ws2[(     quad * 8 + i) * 32 + cc]);
        Bw01[i] = f2bf(Ws2[(32 + quad * 8 + i) * 32 + cc]);
        Bw10[i] = f2bf(Ws2[(     quad * 8 + i) * 32 + 16 + cc]);
        Bw11[i] = f2bf(Ws2[(32 + quad * 8 + i) * 32 + 16 + cc]);
    }
    float bsq0[8], bsq1[8];
    #pragma unroll
    for (int i = 0; i < 8; ++i) {
        bsq0[i] = bs1[quad * 8 + i];
        bsq1[i] = bs1[32 + quad * 8 + i];
    }
    const float bs2c0 = bs2[cc], bs2c1 = bs2[16 + cc];
    __syncthreads();   // su, fe(seq half), szero, swo1 ready

    // ---- spatial pairwise MLP: 4 waves x 8 j ----
    #pragma unroll 2
    for (int jj = 0; jj < 8; ++jj) {
        const int jrow = w * 8 + jj;       // wave-uniform j, 0..31
        float vj0[8], vj1[8];
        #pragma unroll
        for (int i = 0; i < 8; ++i) {
            vj0[i] = su[jrow][quad * 8 + i] - bsq0[i];
            vj1[i] = su[jrow][32 + quad * 8 + i] - bsq1[i];
        }
        float acc0 = 0.0f, acc1 = 0.0f;
        #pragma unroll
        for (int it = 0; it < 2; ++it) {
            const int irow = it * 16 + cc;   // A-frag row m = cc
            const float4 p0 = *(const float4*)&su[irow][quad * 8];
            const float4 p1 = *(const float4*)&su[irow][quad * 8 + 4];
            const float4 p2 = *(const float4*)&su[irow][32 + quad * 8];
            const float4 p3 = *(const float4*)&su[irow][32 + quad * 8 + 4];
            short8 A0, A1;
            A0[0] = f2bf(leakyf(p0.x - vj0[0])); A0[1] = f2bf(leakyf(p0.y - vj0[1]));
            A0[2] = f2bf(leakyf(p0.z - vj0[2])); A0[3] = f2bf(leakyf(p0.w - vj0[3]));
            A0[4] = f2bf(leakyf(p1.x - vj0[4])); A0[5] = f2bf(leakyf(p1.y - vj0[5]));
            A0[6] = f2bf(leakyf(p1.z - vj0[6])); A0[7] = f2bf(leakyf(p1.w - vj0[7]));
            A1[0] = f2bf(leakyf(p2.x - vj1[0])); A1[1] = f2bf(leakyf(p2.y - vj1[1]));
            A1[2] = f2bf(leakyf(p2.z - vj1[2])); A1[3] = f2bf(leakyf(p2.w - vj1[3]));
            A1[4] = f2bf(leakyf(p3.x - vj1[4])); A1[5] = f2bf(leakyf(p3.y - vj1[5]));
            A1[6] = f2bf(leakyf(p3.z - vj1[6])); A1[7] = f2bf(leakyf(p3.w - vj1[7]));
            const floatx4 z4 = {0.f, 0.f, 0.f, 0.f};
            const floatx4 D0 = MFMA16(A1, Bw01, MFMA16(A0, Bw00, z4));
            const floatx4 D1 = MFMA16(A1, Bw11, MFMA16(A0, Bw10, z4));
            #pragma unroll
            for (int r = 0; r < 4; ++r) {
                acc0 += leakyf(D0[r] + bs2c0);
                acc1 += leakyf(D1[r] + bs2c1);
            }
        }
        acc0 += __shfl_xor(acc0, 16, 64); acc0 += __shfl_xor(acc0, 32, 64);
        acc1 += __shfl_xor(acc1, 16, 64); acc1 += __shfl_xor(acc1, 32, 64);
        const int n = index_div[g * NGRP + jrow];
        if (quad == 0) {
            const float pv = (acc0 - szero[cc]) * (1.0f / 31.0f);
            full_enc[n * HH + 32 + cc] = pv;
            fe[jrow][32 + cc] = pv;
        } else if (quad == 1) {
            const float pv = (acc1 - szero[16 + cc]) * (1.0f / 31.0f);
            full_enc[n * HH + 48 + cc] = pv;
            fe[jrow][48 + cc] = pv;
        }
    }
    __syncthreads();

    // ---- head: x_logit = leaky(fe @ Wo1 + bo1) @ Wo2 + bo2 ----
    {
        const int veh = tid >> 3;          // 0..31
        const int p   = tid & 7;
        const int m0  = p * 2;
        float a0 = bo1[m0], a1 = bo1[m0 + 1];
        #pragma unroll
        for (int k = 0; k < HH; ++k) {
            const float f = fe[veh][k];
            const float2 wv = *(const float2*)&swo1[k * 16 + m0];
            a0 = fmaf(f, wv.x, a0);
            a1 = fmaf(f, wv.y, a1);
        }
        a0 = leakyf(a0); a1 = leakyf(a1);
        float l0 = fmaf(a0, Wo2[m0 * 3 + 0], a1 * Wo2[(m0 + 1) * 3 + 0]);
        float l1 = fmaf(a0, Wo2[m0 * 3 + 1], a1 * Wo2[(m0 + 1) * 3 + 1]);
        float l2 = fmaf(a0, Wo2[m0 * 3 + 2], a1 * Wo2[(m0 + 1) * 3 + 2]);
        #pragma unroll
        for (int off = 1; off < 8; off <<= 1) {
            l0 += __shfl_xor(l0, off, 64);
            l1 += __shfl_xor(l1, off, 64);
            l2 += __shfl_xor(l2, off, 64);
        }
        if (p == 0) {
            const int n = index_div[g * NGRP + veh];
            out[n * 3 + 0] = l0 + bo2[0];
            out[n * 3 + 1] = l1 + bo2[1];
            out[n * 3 + 2] = l2 + bo2[2];
        }
    }
}

// ---------------------------------------------------------------------------
extern "C" void kernel_launch(void* const* d_in, const int* in_sizes, int n_in,
                              void* d_out, int out_size, void* d_ws, size_t ws_size,
                              hipStream_t stream) {
    const float* scene     = (const float*)d_in[0];
    const int*   index_div = (const int*)d_in[4];
    const float* W_emb = (const float*)d_in[5];
    const float* b_emb = (const float*)d_in[6];
    const float* Wih_f = (const float*)d_in[7];
    const float* Whh_f = (const float*)d_in[8];
    const float* bih_f = (const float*)d_in[9];
    const float* bhh_f = (const float*)d_in[10];
    const float* Wih_b = (const float*)d_in[11];
    const float* Whh_b = (const float*)d_in[12];
    const float* bih_b = (const float*)d_in[13];
    const float* bhh_b = (const float*)d_in[14];
    const float* Wm  = (const float*)d_in[15];
    const float* bm  = (const float*)d_in[16];
    const float* Ws1 = (const float*)d_in[17];
    const float* bs1 = (const float*)d_in[18];
    const float* Ws2 = (const float*)d_in[19];
    const float* bs2 = (const float*)d_in[20];
    const float* Wo1 = (const float*)d_in[21];
    const float* bo1 = (const float*)d_in[22];
    const float* Wo2 = (const float*)d_in[23];
    const float* bo2 = (const float*)d_in[24];

    const int N = in_sizes[0] / (2 * TT);   // 32768
    const int G = in_sizes[4] / NGRP;       // 1024

    float* out      = (float*)d_out;
    float* full_enc = out + (size_t)N * CC;
    short* hws      = (short*)d_ws;         // 2G * 2048 shorts = 8 MB

    gru_dir_kernel<<<dim3(2 * G), dim3(256), 0, stream>>>(
        scene, index_div, W_emb, b_emb, Wih_f, Whh_f, bih_f, bhh_f,
        Wih_b, Whh_b, bih_b, bhh_b, hws);

    tail_kernel<<<dim3(G), dim3(256), 0, stream>>>(
        scene, index_div, hws, Wm, bm, Ws1, bs1, Ws2, bs2,
        Wo1, bo1, Wo2, bo2, full_enc, out);
}

// Round 11
// 200.492 us; speedup vs baseline: 1.3665x; 1.3665x over previous
//
#include <hip/hip_runtime.h>
#include <hip/hip_bf16.h>

#define TT 16      // in_length
#define EE 32      // embedding size
#define HH 64      // encoder size
#define NGRP 32    // vehicles per group
#define CC 3       // classes

typedef __attribute__((ext_vector_type(8))) short short8;
typedef __attribute__((ext_vector_type(4))) short short4v;
typedef __attribute__((ext_vector_type(4))) float floatx4;

#define MFMA16(a, b, c) __builtin_amdgcn_mfma_f32_16x16x32_bf16((a), (b), (c), 0, 0, 0)

#define RLN2 1.4426950408889634f   // 1/ln2

__device__ __forceinline__ float leakyf(float x) { return fmaxf(x, 0.1f * x); }
__device__ __forceinline__ short f2bf(float x) {   // fp32 -> bf16 RNE (one-time weights)
    unsigned u = __float_as_uint(x);
    return (short)((u + 0x7FFFu + ((u >> 16) & 1u)) >> 16);
}
__device__ __forceinline__ short f2bf_h(float x) { // fp32 -> bf16 round-half-up (per-step)
    return (short)((__float_as_uint(x) + 0x8000u) >> 16);
}
__device__ __forceinline__ float bf2f(short s) {
    return __uint_as_float(((unsigned)(unsigned short)s) << 16);
}
__device__ __forceinline__ short8 ld8bf(const float* __restrict__ p) {
    const float4 a = *(const float4*)p;
    const float4 b = *(const float4*)(p + 4);
    short8 v;
    v[0] = f2bf(a.x); v[1] = f2bf(a.y); v[2] = f2bf(a.z); v[3] = f2bf(a.w);
    v[4] = f2bf(b.x); v[5] = f2bf(b.y); v[6] = f2bf(b.z); v[7] = f2bf(b.w);
    return v;
}
__device__ __forceinline__ short8 ld8bfs(const float* __restrict__ p, float s) {
    const float4 a = *(const float4*)p;
    const float4 b = *(const float4*)(p + 4);
    short8 v;
    v[0] = f2bf(a.x * s); v[1] = f2bf(a.y * s); v[2] = f2bf(a.z * s); v[3] = f2bf(a.w * s);
    v[4] = f2bf(b.x * s); v[5] = f2bf(b.y * s); v[6] = f2bf(b.z * s); v[7] = f2bf(b.w * s);
    return v;
}

// ---------------------------------------------------------------------------
// Kernel 1: ONE GRU DIRECTION per block. Grid 2*G; block 256 thr = 4 waves.
//   R11 = R10 with launch_bounds(256,4): the (*,6) 85-VGPR cap spills the
//   B-frags (R5/R7/R10 — VGPR collapses to 40, 100s of MB scratch traffic);
//   at (*,4) cap=128 the kernel fits (R4/R6/R8/R9: VGPR 64, FETCH ~3 MB) and
//   HW can still co-schedule up to 8 of these blocks/CU (LDS 16.9 KB, VGPR 64).
//   Barrier spans only 4 waves -> many independent barrier groups per CU.
//   One barrier/step: Hf double-buffered (8 KB), X regenerated per step into
//   double-buffered Xb (4 KB). B-frags pre-scaled -1/ln2 (r,z) / 2/ln2 (n);
//   scalar biases post-MFMA; gates via raw exp2+rcp.
//   Final h written frag-packed bf16 to d_ws: hws[bx][2048 shorts].
// ---------------------------------------------------------------------------
__global__ __launch_bounds__(256, 4) void gru_dir_kernel(
    const float* __restrict__ scene, const int* __restrict__ index_div,
    const float* __restrict__ W_emb, const float* __restrict__ b_emb,
    const float* __restrict__ Wih_f, const float* __restrict__ Whh_f,
    const float* __restrict__ bih_f, const float* __restrict__ bhh_f,
    const float* __restrict__ Wih_b, const float* __restrict__ Whh_b,
    const float* __restrict__ bih_b, const float* __restrict__ bhh_b,
    short* __restrict__ hws)
{
    __shared__ float sscene[32][33];             // [c][veh] 4224 B
    __shared__ __align__(16) short Hf[2 * 2 * 2 * 64 * 8];  // [buf][ks][mt][slot][8] 8 KB
    __shared__ __align__(16) short Xb[2 * 2 * 64 * 8];      // [buf][mt][lane][8]     4 KB

    const int bx   = blockIdx.x;
    const int g    = bx >> 1;
    const int dir  = bx & 1;
    const int tid  = threadIdx.x;
    const int lane = tid & 63;
    const int wd   = __builtin_amdgcn_readfirstlane(tid >> 6);  // 0..3
    const int cc   = lane & 15;
    const int quad = lane >> 4;
    const int j    = wd * 16 + cc;            // hidden dim / gate column
    const int ks_w = j >> 5;
    const int qa_w = (j >> 3) & 3;
    const int ii_w = j & 7;

    // ---- stage gathered scene rows into sscene[c][veh] ----
    #pragma unroll
    for (int rep = 0; rep < 4; ++rep) {
        const int idx = tid + rep * 256;
        const int v = idx >> 5, c = idx & 31;
        const int n = index_div[g * NGRP + v];
        sscene[c][v] = scene[n * 32 + c];
    }

    // ---- per-wave B-frags (this block's dir), pre-scaled; scalar biases ----
    const float* Wih = dir ? Wih_b : Wih_f;
    const float* Whh = dir ? Whh_b : Whh_f;
    const float* bih = dir ? bih_b : bih_f;
    const float* bhh = dir ? bhh_b : bhh_f;
    const int k0 = quad * 8;
    const float SRZ = -RLN2, SN = 2.0f * RLN2;
    const short8 Br0  = ld8bfs(Whh + (j      ) * 64 + k0,      SRZ);
    const short8 Br1  = ld8bfs(Whh + (j      ) * 64 + 32 + k0, SRZ);
    const short8 Br2  = ld8bfs(Wih + (j      ) * 32 + k0,      SRZ);
    const short8 Bz0  = ld8bfs(Whh + (j +  64) * 64 + k0,      SRZ);
    const short8 Bz1  = ld8bfs(Whh + (j +  64) * 64 + 32 + k0, SRZ);
    const short8 Bz2  = ld8bfs(Wih + (j +  64) * 32 + k0,      SRZ);
    const short8 Bhn0 = ld8bfs(Whh + (j + 128) * 64 + k0,      SN);
    const short8 Bhn1 = ld8bfs(Whh + (j + 128) * 64 + 32 + k0, SN);
    const short8 Bxn  = ld8bfs(Wih + (j + 128) * 32 + k0,      SN);
    const float vb_r  = SRZ * (bih[j] + bhh[j]);
    const float vb_z  = SRZ * (bih[j + 64] + bhh[j + 64]);
    const float vb_xn = SN * bih[j + 128];
    const float vb_hn = SN * bhh[j + 128];

    // ---- per-thread emb generator (256 threads; weights in 12 regs) ----
    const int veh_x = tid & 31;
    const int q2    = tid >> 5;               // 0..7
    const int e0    = q2 * 4;
    float w0e[4], w1e[4], bbe[4];
    #pragma unroll
    for (int d = 0; d < 4; ++d) {
        w0e[d] = W_emb[e0 + d];
        w1e[d] = W_emb[EE + e0 + d];
        bbe[d] = b_emb[e0 + d];
    }
    // X-frag: [mt=veh>>4][slot=(e>>3)*16+(veh&15)] elem e&7
    const int xoff = ((veh_x >> 4) * 64 + (q2 >> 1) * 16 + (veh_x & 15)) * 8
                   + (q2 & 1) * 4;            // + buf*1024

    __syncthreads();   // sscene ready

    // ---- zero Hf buf0 + prefill Xb buf0 for step 0 ----
    {
        const short8 z8 = {0, 0, 0, 0, 0, 0, 0, 0};
        *(short8*)&Hf[tid * 8] = z8;          // 256 x 16B = buf0
        const int t0 = dir ? (TT - 1) : 0;
        const float xs = sscene[t0][veh_x];
        const float ys = sscene[16 + t0][veh_x];
        short4v v;
        #pragma unroll
        for (int d = 0; d < 4; ++d)
            v[d] = f2bf_h(leakyf(fmaf(xs, w0e[d], fmaf(ys, w1e[d], bbe[d]))));
        *(short4v*)&Xb[xoff] = v;
    }

    float h_reg[8];
    #pragma unroll
    for (int i = 0; i < 8; ++i) h_reg[i] = 0.0f;

    __syncthreads();

    // ---- GRU main loop: ONE barrier per step ----
    #pragma unroll 2
    for (int s = 0; s < TT; ++s) {
        const int pb = s & 1, nb = pb ^ 1;
        const short* HfD = &Hf[pb * 2048];
        short*       HfN = &Hf[nb * 2048];
        const short* XbD = &Xb[pb * 1024];
        #pragma unroll
        for (int mt = 0; mt < 2; ++mt) {
            const short8 Ah0 = *(const short8*)&HfD[((0 * 2 + mt) * 64 + lane) * 8];
            const short8 Ah1 = *(const short8*)&HfD[((1 * 2 + mt) * 64 + lane) * 8];
            const short8 Axx = *(const short8*)&XbD[(mt * 64 + lane) * 8];
            const floatx4 z4 = {0.f, 0.f, 0.f, 0.f};
            const floatx4 ar  = MFMA16(Axx, Br2, MFMA16(Ah1, Br1, MFMA16(Ah0, Br0, z4)));
            const floatx4 az  = MFMA16(Axx, Bz2, MFMA16(Ah1, Bz1, MFMA16(Ah0, Bz0, z4)));
            const floatx4 ahn = MFMA16(Ah1, Bhn1, MFMA16(Ah0, Bhn0, z4));
            const floatx4 axn = MFMA16(Axx, Bxn, z4);
            #pragma unroll
            for (int r = 0; r < 4; ++r) {
                const float rr = __builtin_amdgcn_rcpf(1.0f + __builtin_amdgcn_exp2f(ar[r] + vb_r));
                const float zz = __builtin_amdgcn_rcpf(1.0f + __builtin_amdgcn_exp2f(az[r] + vb_z));
                const float y  = fmaf(rr, ahn[r] + vb_hn, axn[r] + vb_xn);
                const float ng = fmaf(-2.0f,
                                      __builtin_amdgcn_rcpf(__builtin_amdgcn_exp2f(y) + 1.0f),
                                      1.0f);
                const float h0 = h_reg[mt * 4 + r];
                h_reg[mt * 4 + r] = fmaf(zz, h0 - ng, ng);  // (1-z)*ng + z*h
            }
        }
        // write new h into buf nb (natural A-frag slots); regen X for s+1
        #pragma unroll
        for (int mt = 0; mt < 2; ++mt) {
            #pragma unroll
            for (int r = 0; r < 4; ++r) {
                const int slot = qa_w * 16 + quad * 4 + r;
                HfN[((ks_w * 2 + mt) * 64 + slot) * 8 + ii_w] = f2bf_h(h_reg[mt * 4 + r]);
            }
        }
        if (s + 1 < TT) {
            const int tn = dir ? (TT - 2 - s) : (s + 1);
            const float xs = sscene[tn][veh_x];
            const float ys = sscene[16 + tn][veh_x];
            short4v v;
            #pragma unroll
            for (int d = 0; d < 4; ++d)
                v[d] = f2bf_h(leakyf(fmaf(xs, w0e[d], fmaf(ys, w1e[d], bbe[d]))));
            *(short4v*)&Xb[xoff + nb * 1024] = v;
        }
        __syncthreads();
    }
    // Final h in Hf buf0 (s=15 wrote nb=0). Copy frag-packed to workspace.
    *(short8*)&hws[(size_t)bx * 2048 + tid * 8] = *(const short8*)&Hf[tid * 8];
}

// ---------------------------------------------------------------------------
// Kernel 2: seq_enc epilogue (MFMA, reads h frags from ws) + spatial pairwise
// MLP (MFMA) + head. One block per group, 256 thr = 4 waves.
// ---------------------------------------------------------------------------
__global__ __launch_bounds__(256, 4) void tail_kernel(
    const float* __restrict__ scene, const int* __restrict__ index_div,
    const short* __restrict__ hws,
    const float* __restrict__ Wm, const float* __restrict__ bm,
    const float* __restrict__ Ws1, const float* __restrict__ bs1,
    const float* __restrict__ Ws2, const float* __restrict__ bs2,
    const float* __restrict__ Wo1, const float* __restrict__ bo1,
    const float* __restrict__ Wo2, const float* __restrict__ bo2,
    float* __restrict__ full_enc, float* __restrict__ out)
{
    __shared__ float sscene[32][33];   // 4.2 KB
    __shared__ float su[NGRP][68];     // 8.7 KB
    __shared__ float fe[NGRP][68];     // 8.7 KB (cols 0..63 used)
    __shared__ float swo1[1024];       // 4 KB
    __shared__ float szero[32];

    const int g    = blockIdx.x;
    const int tid  = threadIdx.x;
    const int lane = tid & 63;
    const int w    = __builtin_amdgcn_readfirstlane(tid >> 6);  // 0..3
    const int cc   = lane & 15;
    const int quad = lane >> 4;

    // ---- stage sscene[c][veh], swo1, szero ----
    #pragma unroll
    for (int rep = 0; rep < 4; ++rep) {
        const int idx = tid + rep * 256;
        const int v = idx >> 5, c = idx & 31;
        const int n = index_div[g * NGRP + v];
        sscene[c][v] = scene[n * 32 + c];
    }
    *(float4*)&swo1[tid * 4] = *(const float4*)&Wo1[tid * 4];
    if (tid < 32) {
        float zs = bs2[tid];
        #pragma unroll
        for (int d = 0; d < HH; ++d) zs = fmaf(leakyf(bs1[d]), Ws2[d * 32 + tid], zs);
        szero[tid] = leakyf(zs);
    }
    __syncthreads();

    // ---- su = feat @ Ws1 ----
    {
        const int v  = tid >> 3;
        const int d0 = (tid & 7) * 8;
        float acc[8];
        #pragma unroll
        for (int i = 0; i < 8; ++i) acc[i] = 0.0f;
        #pragma unroll
        for (int e = 0; e < EE; ++e) {
            const float f = sscene[e][v];
            const float4 w0 = *(const float4*)&Ws1[e * 64 + d0];
            const float4 w1 = *(const float4*)&Ws1[e * 64 + d0 + 4];
            acc[0] = fmaf(f, w0.x, acc[0]); acc[1] = fmaf(f, w0.y, acc[1]);
            acc[2] = fmaf(f, w0.z, acc[2]); acc[3] = fmaf(f, w0.w, acc[3]);
            acc[4] = fmaf(f, w1.x, acc[4]); acc[5] = fmaf(f, w1.y, acc[5]);
            acc[6] = fmaf(f, w1.z, acc[6]); acc[7] = fmaf(f, w1.w, acc[7]);
        }
        #pragma unroll
        for (int i = 0; i < 8; ++i) su[v][d0 + i] = acc[i];
    }

    // ---- seq_enc epilogue: hm = 0.5*(h_f+h_b) as A-frags from ws, MFMA ----
    {
        const int nt   = w >> 1;
        const int mt_e = w & 1;
        const int n_col = nt * 16 + cc;
        short8 Bm0, Bm1;
        #pragma unroll
        for (int i = 0; i < 8; ++i) {
            Bm0[i] = f2bf(Wm[(     quad * 8 + i) * 32 + n_col]);
            Bm1[i] = f2bf(Wm[(32 + quad * 8 + i) * 32 + n_col]);
        }
        short8 A0, A1;
        #pragma unroll
        for (int ks = 0; ks < 2; ++ks) {
            const short8 F = *(const short8*)&hws[(size_t)(g * 2 + 0) * 2048 + ((ks * 2 + mt_e) * 64 + lane) * 8];
            const short8 B = *(const short8*)&hws[(size_t)(g * 2 + 1) * 2048 + ((ks * 2 + mt_e) * 64 + lane) * 8];
            #pragma unroll
            for (int i = 0; i < 8; ++i) {
                const short v = f2bf(0.5f * (bf2f(F[i]) + bf2f(B[i])));
                if (ks == 0) A0[i] = v; else A1[i] = v;
            }
        }
        const floatx4 z4 = {0.f, 0.f, 0.f, 0.f};
        const floatx4 acc = MFMA16(A1, Bm1, MFMA16(A0, Bm0, z4));
        const float bmn = bm[n_col];
        #pragma unroll
        for (int r = 0; r < 4; ++r) {
            const int veh = mt_e * 16 + quad * 4 + r;
            const float sv = leakyf(acc[r] + bmn);
            const int n = index_div[g * NGRP + veh];
            full_enc[n * HH + n_col] = sv;
            fe[veh][n_col] = sv;
        }
    }

    // ---- spatial B-frags ----
    short8 Bw00, Bw01, Bw10, Bw11;
    #pragma unroll
    for (int i = 0; i < 8; ++i) {
        Bw00[i] = f2bf(Ws2[(     quad * 8 + i) * 32 + cc]);
        Bw01[i] = f2bf(Ws2[(32 + quad * 8 + i) * 32 + cc]);
        Bw10[i] = f2bf(Ws2[(     quad * 8 + i) * 32 + 16 + cc]);
        Bw11[i] = f2bf(Ws2[(32 + quad * 8 + i) * 32 + 16 + cc]);
    }
    float bsq0[8], bsq1[8];
    #pragma unroll
    for (int i = 0; i < 8; ++i) {
        bsq0[i] = bs1[quad * 8 + i];
        bsq1[i] = bs1[32 + quad * 8 + i];
    }
    const float bs2c0 = bs2[cc], bs2c1 = bs2[16 + cc];
    __syncthreads();   // su, fe(seq half), szero, swo1 ready

    // ---- spatial pairwise MLP: 4 waves x 8 j ----
    #pragma unroll 2
    for (int jj = 0; jj < 8; ++jj) {
        const int jrow = w * 8 + jj;       // wave-uniform j, 0..31
        float vj0[8], vj1[8];
        #pragma unroll
        for (int i = 0; i < 8; ++i) {
            vj0[i] = su[jrow][quad * 8 + i] - bsq0[i];
            vj1[i] = su[jrow][32 + quad * 8 + i] - bsq1[i];
        }
        float acc0 = 0.0f, acc1 = 0.0f;
        #pragma unroll
        for (int it = 0; it < 2; ++it) {
            const int irow = it * 16 + cc;   // A-frag row m = cc
            const float4 p0 = *(const float4*)&su[irow][quad * 8];
            const float4 p1 = *(const float4*)&su[irow][quad * 8 + 4];
            const float4 p2 = *(const float4*)&su[irow][32 + quad * 8];
            const float4 p3 = *(const float4*)&su[irow][32 + quad * 8 + 4];
            short8 A0, A1;
            A0[0] = f2bf(leakyf(p0.x - vj0[0])); A0[1] = f2bf(leakyf(p0.y - vj0[1]));
            A0[2] = f2bf(leakyf(p0.z - vj0[2])); A0[3] = f2bf(leakyf(p0.w - vj0[3]));
            A0[4] = f2bf(leakyf(p1.x - vj0[4])); A0[5] = f2bf(leakyf(p1.y - vj0[5]));
            A0[6] = f2bf(leakyf(p1.z - vj0[6])); A0[7] = f2bf(leakyf(p1.w - vj0[7]));
            A1[0] = f2bf(leakyf(p2.x - vj1[0])); A1[1] = f2bf(leakyf(p2.y - vj1[1]));
            A1[2] = f2bf(leakyf(p2.z - vj1[2])); A1[3] = f2bf(leakyf(p2.w - vj1[3]));
            A1[4] = f2bf(leakyf(p3.x - vj1[4])); A1[5] = f2bf(leakyf(p3.y - vj1[5]));
            A1[6] = f2bf(leakyf(p3.z - vj1[6])); A1[7] = f2bf(leakyf(p3.w - vj1[7]));
            const floatx4 z4 = {0.f, 0.f, 0.f, 0.f};
            const floatx4 D0 = MFMA16(A1, Bw01, MFMA16(A0, Bw00, z4));
            const floatx4 D1 = MFMA16(A1, Bw11, MFMA16(A0, Bw10, z4));
            #pragma unroll
            for (int r = 0; r < 4; ++r) {
                acc0 += leakyf(D0[r] + bs2c0);
                acc1 += leakyf(D1[r] + bs2c1);
            }
        }
        acc0 += __shfl_xor(acc0, 16, 64); acc0 += __shfl_xor(acc0, 32, 64);
        acc1 += __shfl_xor(acc1, 16, 64); acc1 += __shfl_xor(acc1, 32, 64);
        const int n = index_div[g * NGRP + jrow];
        if (quad == 0) {
            const float pv = (acc0 - szero[cc]) * (1.0f / 31.0f);
            full_enc[n * HH + 32 + cc] = pv;
            fe[jrow][32 + cc] = pv;
        } else if (quad == 1) {
            const float pv = (acc1 - szero[16 + cc]) * (1.0f / 31.0f);
            full_enc[n * HH + 48 + cc] = pv;
            fe[jrow][48 + cc] = pv;
        }
    }
    __syncthreads();

    // ---- head: x_logit = leaky(fe @ Wo1 + bo1) @ Wo2 + bo2 ----
    {
        const int veh = tid >> 3;          // 0..31
        const int p   = tid & 7;
        const int m0  = p * 2;
        float a0 = bo1[m0], a1 = bo1[m0 + 1];
        #pragma unroll
        for (int k = 0; k < HH; ++k) {
            const float f = fe[veh][k];
            const float2 wv = *(const float2*)&swo1[k * 16 + m0];
            a0 = fmaf(f, wv.x, a0);
            a1 = fmaf(f, wv.y, a1);
        }
        a0 = leakyf(a0); a1 = leakyf(a1);
        float l0 = fmaf(a0, Wo2[m0 * 3 + 0], a1 * Wo2[(m0 + 1) * 3 + 0]);
        float l1 = fmaf(a0, Wo2[m0 * 3 + 1], a1 * Wo2[(m0 + 1) * 3 + 1]);
        float l2 = fmaf(a0, Wo2[m0 * 3 + 2], a1 * Wo2[(m0 + 1) * 3 + 2]);
        #pragma unroll
        for (int off = 1; off < 8; off <<= 1) {
            l0 += __shfl_xor(l0, off, 64);
            l1 += __shfl_xor(l1, off, 64);
            l2 += __shfl_xor(l2, off, 64);
        }
        if (p == 0) {
            const int n = index_div[g * NGRP + veh];
            out[n * 3 + 0] = l0 + bo2[0];
            out[n * 3 + 1] = l1 + bo2[1];
            out[n * 3 + 2] = l2 + bo2[2];
        }
    }
}

// ---------------------------------------------------------------------------
extern "C" void kernel_launch(void* const* d_in, const int* in_sizes, int n_in,
                              void* d_out, int out_size, void* d_ws, size_t ws_size,
                              hipStream_t stream) {
    const float* scene     = (const float*)d_in[0];
    const int*   index_div = (const int*)d_in[4];
    const float* W_emb = (const float*)d_in[5];
    const float* b_emb = (const float*)d_in[6];
    const float* Wih_f = (const float*)d_in[7];
    const float* Whh_f = (const float*)d_in[8];
    const float* bih_f = (const float*)d_in[9];
    const float* bhh_f = (const float*)d_in[10];
    const float* Wih_b = (const float*)d_in[11];
    const float* Whh_b = (const float*)d_in[12];
    const float* bih_b = (const float*)d_in[13];
    const float* bhh_b = (const float*)d_in[14];
    const float* Wm  = (const float*)d_in[15];
    const float* bm  = (const float*)d_in[16];
    const float* Ws1 = (const float*)d_in[17];
    const float* bs1 = (const float*)d_in[18];
    const float* Ws2 = (const float*)d_in[19];
    const float* bs2 = (const float*)d_in[20];
    const float* Wo1 = (const float*)d_in[21];
    const float* bo1 = (const float*)d_in[22];
    const float* Wo2 = (const float*)d_in[23];
    const float* bo2 = (const float*)d_in[24];

    const int N = in_sizes[0] / (2 * TT);   // 32768
    const int G = in_sizes[4] / NGRP;       // 1024

    float* out      = (float*)d_out;
    float* full_enc = out + (size_t)N * CC;
    short* hws      = (short*)d_ws;         // 2G * 2048 shorts = 8 MB

    gru_dir_kernel<<<dim3(2 * G), dim3(256), 0, stream>>>(
        scene, index_div, W_emb, b_emb, Wih_f, Whh_f, bih_f, bhh_f,
        Wih_b, Whh_b, bih_b, bhh_b, hws);

    tail_kernel<<<dim3(G), dim3(256), 0, stream>>>(
        scene, index_div, hws, Wm, bm, Ws1, bs1, Ws2, bs2,
        Wo1, bo1, Wo2, bo2, full_enc, out);
}

// Round 12
// 200.401 us; speedup vs baseline: 1.3671x; 1.0005x over previous
//
#include <hip/hip_runtime.h>
#include <hip/hip_bf16.h>

#define TT 16      // in_length
#define EE 32      // embedding size
#define HH 64      // encoder size
#define NGRP 32    // vehicles per group
#define CC 3       // classes

typedef __attribute__((ext_vector_type(8))) short short8;
typedef __attribute__((ext_vector_type(4))) short short4v;
typedef __attribute__((ext_vector_type(4))) float floatx4;

#define MFMA16(a, b, c) __builtin_amdgcn_mfma_f32_16x16x32_bf16((a), (b), (c), 0, 0, 0)

#define RLN2 1.4426950408889634f   // 1/ln2

__device__ __forceinline__ float leakyf(float x) { return fmaxf(x, 0.1f * x); }
__device__ __forceinline__ short f2bf(float x) {   // fp32 -> bf16 RNE (one-time weights)
    unsigned u = __float_as_uint(x);
    return (short)((u + 0x7FFFu + ((u >> 16) & 1u)) >> 16);
}
__device__ __forceinline__ short f2bf_h(float x) { // fp32 -> bf16 round-half-up (per-step)
    return (short)((__float_as_uint(x) + 0x8000u) >> 16);
}
__device__ __forceinline__ float bf2f(short s) {
    return __uint_as_float(((unsigned)(unsigned short)s) << 16);
}
__device__ __forceinline__ short8 ld8bf(const float* __restrict__ p) {
    const float4 a = *(const float4*)p;
    const float4 b = *(const float4*)(p + 4);
    short8 v;
    v[0] = f2bf(a.x); v[1] = f2bf(a.y); v[2] = f2bf(a.z); v[3] = f2bf(a.w);
    v[4] = f2bf(b.x); v[5] = f2bf(b.y); v[6] = f2bf(b.z); v[7] = f2bf(b.w);
    return v;
}
__device__ __forceinline__ short8 ld8bfs(const float* __restrict__ p, float s) {
    const float4 a = *(const float4*)p;
    const float4 b = *(const float4*)(p + 4);
    short8 v;
    v[0] = f2bf(a.x * s); v[1] = f2bf(a.y * s); v[2] = f2bf(a.z * s); v[3] = f2bf(a.w * s);
    v[4] = f2bf(b.x * s); v[5] = f2bf(b.y * s); v[6] = f2bf(b.z * s); v[7] = f2bf(b.w * s);
    return v;
}

// ---------------------------------------------------------------------------
// Kernel 1: ONE GRU DIRECTION, TWO GROUPS (64 vehicles) per block.
//   Grid = G (1024): g2 = bx>>1 covers groups {2g2, 2g2+1}; dir = bx&1.
//   Block 256 thr = 4 waves; wave wd owns gate cols [16wd,16wd+16).
//   Per thread: 16 independent gate values (4 m-tiles) -> 2x the ILP of R11 to
//   hide quarter-rate exp2/rcp latency; B-frag loads/barriers amortize 2x.
//   One barrier/step: Hf double-buffered (16 KB), X regen into dbuf Xb (8 KB).
//   launch_bounds(256,4): cap 128 — the (*,6) 85-cap spills B-frags
//   (R5/R7/R10); (*,4) is 4-for-4 clean (R4/R6/R8/R9/R11).
//   Final h -> d_ws frag-packed bf16, per-group layout matching tail_kernel.
// ---------------------------------------------------------------------------
__global__ __launch_bounds__(256, 4) void gru_dir2_kernel(
    const float* __restrict__ scene, const int* __restrict__ index_div,
    const float* __restrict__ W_emb, const float* __restrict__ b_emb,
    const float* __restrict__ Wih_f, const float* __restrict__ Whh_f,
    const float* __restrict__ bih_f, const float* __restrict__ bhh_f,
    const float* __restrict__ Wih_b, const float* __restrict__ Whh_b,
    const float* __restrict__ bih_b, const float* __restrict__ bhh_b,
    short* __restrict__ hws)
{
    __shared__ float sscene[32][65];                        // [c][veh0..63] 8.3 KB
    __shared__ __align__(16) short Hf[2 * 2 * 4 * 64 * 8];  // [buf][ks][mt4][slot][8] 16 KB
    __shared__ __align__(16) short Xb[2 * 4 * 64 * 8];      // [buf][mt4][lane][8]      8 KB

    const int bx   = blockIdx.x;
    const int g2   = bx >> 1;       // group-pair index
    const int dir  = bx & 1;
    const int tid  = threadIdx.x;
    const int lane = tid & 63;
    const int wd   = __builtin_amdgcn_readfirstlane(tid >> 6);  // 0..3
    const int cc   = lane & 15;
    const int quad = lane >> 4;
    const int j    = wd * 16 + cc;            // gate column
    const int ks_w = j >> 5;
    const int qa_w = (j >> 3) & 3;
    const int ii_w = j & 7;

    // ---- stage gathered scene rows: 64 veh x 32 cols ----
    #pragma unroll
    for (int rep = 0; rep < 8; ++rep) {
        const int idx = tid + rep * 256;
        const int v = idx >> 5, c = idx & 31;
        const int n = index_div[g2 * 64 + v];
        sscene[c][v] = scene[n * 32 + c];
    }

    // ---- per-wave B-frags (this block's dir), pre-scaled; scalar biases ----
    const float* Wih = dir ? Wih_b : Wih_f;
    const float* Whh = dir ? Whh_b : Whh_f;
    const float* bih = dir ? bih_b : bih_f;
    const float* bhh = dir ? bhh_b : bhh_f;
    const int k0 = quad * 8;
    const float SRZ = -RLN2, SN = 2.0f * RLN2;
    const short8 Br0  = ld8bfs(Whh + (j      ) * 64 + k0,      SRZ);
    const short8 Br1  = ld8bfs(Whh + (j      ) * 64 + 32 + k0, SRZ);
    const short8 Br2  = ld8bfs(Wih + (j      ) * 32 + k0,      SRZ);
    const short8 Bz0  = ld8bfs(Whh + (j +  64) * 64 + k0,      SRZ);
    const short8 Bz1  = ld8bfs(Whh + (j +  64) * 64 + 32 + k0, SRZ);
    const short8 Bz2  = ld8bfs(Wih + (j +  64) * 32 + k0,      SRZ);
    const short8 Bhn0 = ld8bfs(Whh + (j + 128) * 64 + k0,      SN);
    const short8 Bhn1 = ld8bfs(Whh + (j + 128) * 64 + 32 + k0, SN);
    const short8 Bxn  = ld8bfs(Wih + (j + 128) * 32 + k0,      SN);
    const float vb_r  = SRZ * (bih[j] + bhh[j]);
    const float vb_z  = SRZ * (bih[j + 64] + bhh[j + 64]);
    const float vb_xn = SN * bih[j + 128];
    const float vb_hn = SN * bhh[j + 128];

    // ---- per-thread emb generator: 2 vehicles x 4 e-dims (weights 12 regs) ----
    const int veh_x = tid & 31;               // vehicle in first half; +32 = second
    const int q2e   = tid >> 5;               // 0..7
    const int e0    = q2e * 4;
    float w0e[4], w1e[4], bbe[4];
    #pragma unroll
    for (int d = 0; d < 4; ++d) {
        w0e[d] = W_emb[e0 + d];
        w1e[d] = W_emb[EE + e0 + d];
        bbe[d] = b_emb[e0 + d];
    }
    // X-frag addr for veh: [mt=veh>>4][slot=(e0>>3)*16+(veh&15)] elem (q2e&1)*4
    const int xoff0 = ((veh_x >> 4) * 64 + (q2e >> 1) * 16 + (veh_x & 15)) * 8
                    + (q2e & 1) * 4;          // + buf*2048 ; veh+32 -> +1024

    __syncthreads();   // sscene ready

    // ---- zero Hf buf0 (4096 shorts) + prefill Xb buf0 for step 0 ----
    {
        const short8 z8 = {0, 0, 0, 0, 0, 0, 0, 0};
        *(short8*)&Hf[tid * 8] = z8;
        *(short8*)&Hf[2048 + tid * 8] = z8;
        const int t0 = dir ? (TT - 1) : 0;
        const float xs0 = sscene[t0][veh_x];
        const float ys0 = sscene[16 + t0][veh_x];
        const float xs1 = sscene[t0][veh_x + 32];
        const float ys1 = sscene[16 + t0][veh_x + 32];
        short4v v0, v1;
        #pragma unroll
        for (int d = 0; d < 4; ++d) {
            v0[d] = f2bf_h(leakyf(fmaf(xs0, w0e[d], fmaf(ys0, w1e[d], bbe[d]))));
            v1[d] = f2bf_h(leakyf(fmaf(xs1, w0e[d], fmaf(ys1, w1e[d], bbe[d]))));
        }
        *(short4v*)&Xb[xoff0] = v0;
        *(short4v*)&Xb[xoff0 + 1024] = v1;
    }

    float h_reg[16];
    #pragma unroll
    for (int i = 0; i < 16; ++i) h_reg[i] = 0.0f;

    __syncthreads();

    // ---- GRU main loop: ONE barrier per step; 4 m-tiles per wave ----
    #pragma unroll 2
    for (int s = 0; s < TT; ++s) {
        const int pb = s & 1, nb = pb ^ 1;
        const short* HfD = &Hf[pb * 4096];
        short*       HfN = &Hf[nb * 4096];
        const short* XbD = &Xb[pb * 2048];
        #pragma unroll
        for (int mt = 0; mt < 4; ++mt) {
            const short8 Ah0 = *(const short8*)&HfD[((0 * 4 + mt) * 64 + lane) * 8];
            const short8 Ah1 = *(const short8*)&HfD[((1 * 4 + mt) * 64 + lane) * 8];
            const short8 Axx = *(const short8*)&XbD[(mt * 64 + lane) * 8];
            const floatx4 z4 = {0.f, 0.f, 0.f, 0.f};
            const floatx4 ar  = MFMA16(Axx, Br2, MFMA16(Ah1, Br1, MFMA16(Ah0, Br0, z4)));
            const floatx4 az  = MFMA16(Axx, Bz2, MFMA16(Ah1, Bz1, MFMA16(Ah0, Bz0, z4)));
            const floatx4 ahn = MFMA16(Ah1, Bhn1, MFMA16(Ah0, Bhn0, z4));
            const floatx4 axn = MFMA16(Axx, Bxn, z4);
            #pragma unroll
            for (int r = 0; r < 4; ++r) {
                const float rr = __builtin_amdgcn_rcpf(1.0f + __builtin_amdgcn_exp2f(ar[r] + vb_r));
                const float zz = __builtin_amdgcn_rcpf(1.0f + __builtin_amdgcn_exp2f(az[r] + vb_z));
                const float y  = fmaf(rr, ahn[r] + vb_hn, axn[r] + vb_xn);
                const float ng = fmaf(-2.0f,
                                      __builtin_amdgcn_rcpf(__builtin_amdgcn_exp2f(y) + 1.0f),
                                      1.0f);
                const float h0 = h_reg[mt * 4 + r];
                h_reg[mt * 4 + r] = fmaf(zz, h0 - ng, ng);  // (1-z)*ng + z*h
            }
        }
        // write new h into buf nb (A-frag slots); regen X for s+1
        #pragma unroll
        for (int mt = 0; mt < 4; ++mt) {
            #pragma unroll
            for (int r = 0; r < 4; ++r) {
                const int slot = qa_w * 16 + quad * 4 + r;
                HfN[((ks_w * 4 + mt) * 64 + slot) * 8 + ii_w] = f2bf_h(h_reg[mt * 4 + r]);
            }
        }
        if (s + 1 < TT) {
            const int tn = dir ? (TT - 2 - s) : (s + 1);
            const float xs0 = sscene[tn][veh_x];
            const float ys0 = sscene[16 + tn][veh_x];
            const float xs1 = sscene[tn][veh_x + 32];
            const float ys1 = sscene[16 + tn][veh_x + 32];
            short4v v0, v1;
            #pragma unroll
            for (int d = 0; d < 4; ++d) {
                v0[d] = f2bf_h(leakyf(fmaf(xs0, w0e[d], fmaf(ys0, w1e[d], bbe[d]))));
                v1[d] = f2bf_h(leakyf(fmaf(xs1, w0e[d], fmaf(ys1, w1e[d], bbe[d]))));
            }
            *(short4v*)&Xb[nb * 2048 + xoff0] = v0;
            *(short4v*)&Xb[nb * 2048 + xoff0 + 1024] = v1;
        }
        __syncthreads();
    }
    // Final h in Hf buf0 ([ks][mt4][slot][8]). Copy per-group to workspace in
    // tail layout: hws[(group*2+dir)*2048 + ((ks*2+mte)*64+slot)*8].
    #pragma unroll
    for (int c2 = 0; c2 < 2; ++c2) {
        const int chunk = tid + c2 * 256;        // 0..511 = [ks][mt][slot]
        const int slot  = chunk & 63;
        const int mtc   = (chunk >> 6) & 3;
        const int ksc   = chunk >> 8;
        const int grp   = mtc >> 1, mte = mtc & 1;
        const size_t dst = ((size_t)((2 * g2 + grp) * 2 + dir) * 2048)
                         + (size_t)(((ksc * 2 + mte) * 64 + slot) * 8);
        *(short8*)&hws[dst] = *(const short8*)&Hf[((ksc * 4 + mtc) * 64 + slot) * 8];
    }
}

// ---------------------------------------------------------------------------
// Kernel 2: seq_enc epilogue (MFMA, reads h frags from ws) + spatial pairwise
// MLP (MFMA) + head. One block per group, 256 thr = 4 waves. (R11-proven.)
// ---------------------------------------------------------------------------
__global__ __launch_bounds__(256, 4) void tail_kernel(
    const float* __restrict__ scene, const int* __restrict__ index_div,
    const short* __restrict__ hws,
    const float* __restrict__ Wm, const float* __restrict__ bm,
    const float* __restrict__ Ws1, const float* __restrict__ bs1,
    const float* __restrict__ Ws2, const float* __restrict__ bs2,
    const float* __restrict__ Wo1, const float* __restrict__ bo1,
    const float* __restrict__ Wo2, const float* __restrict__ bo2,
    float* __restrict__ full_enc, float* __restrict__ out)
{
    __shared__ float sscene[32][33];   // 4.2 KB
    __shared__ float su[NGRP][68];     // 8.7 KB
    __shared__ float fe[NGRP][68];     // 8.7 KB (cols 0..63 used)
    __shared__ float swo1[1024];       // 4 KB
    __shared__ float szero[32];

    const int g    = blockIdx.x;
    const int tid  = threadIdx.x;
    const int lane = tid & 63;
    const int w    = __builtin_amdgcn_readfirstlane(tid >> 6);  // 0..3
    const int cc   = lane & 15;
    const int quad = lane >> 4;

    #pragma unroll
    for (int rep = 0; rep < 4; ++rep) {
        const int idx = tid + rep * 256;
        const int v = idx >> 5, c = idx & 31;
        const int n = index_div[g * NGRP + v];
        sscene[c][v] = scene[n * 32 + c];
    }
    *(float4*)&swo1[tid * 4] = *(const float4*)&Wo1[tid * 4];
    if (tid < 32) {
        float zs = bs2[tid];
        #pragma unroll
        for (int d = 0; d < HH; ++d) zs = fmaf(leakyf(bs1[d]), Ws2[d * 32 + tid], zs);
        szero[tid] = leakyf(zs);
    }
    __syncthreads();

    // su = feat @ Ws1
    {
        const int v  = tid >> 3;
        const int d0 = (tid & 7) * 8;
        float acc[8];
        #pragma unroll
        for (int i = 0; i < 8; ++i) acc[i] = 0.0f;
        #pragma unroll
        for (int e = 0; e < EE; ++e) {
            const float f = sscene[e][v];
            const float4 w0 = *(const float4*)&Ws1[e * 64 + d0];
            const float4 w1 = *(const float4*)&Ws1[e * 64 + d0 + 4];
            acc[0] = fmaf(f, w0.x, acc[0]); acc[1] = fmaf(f, w0.y, acc[1]);
            acc[2] = fmaf(f, w0.z, acc[2]); acc[3] = fmaf(f, w0.w, acc[3]);
            acc[4] = fmaf(f, w1.x, acc[4]); acc[5] = fmaf(f, w1.y, acc[5]);
            acc[6] = fmaf(f, w1.z, acc[6]); acc[7] = fmaf(f, w1.w, acc[7]);
        }
        #pragma unroll
        for (int i = 0; i < 8; ++i) su[v][d0 + i] = acc[i];
    }

    // seq_enc epilogue
    {
        const int nt   = w >> 1;
        const int mt_e = w & 1;
        const int n_col = nt * 16 + cc;
        short8 Bm0, Bm1;
        #pragma unroll
        for (int i = 0; i < 8; ++i) {
            Bm0[i] = f2bf(Wm[(     quad * 8 + i) * 32 + n_col]);
            Bm1[i] = f2bf(Wm[(32 + quad * 8 + i) * 32 + n_col]);
        }
        short8 A0, A1;
        #pragma unroll
        for (int ks = 0; ks < 2; ++ks) {
            const short8 F = *(const short8*)&hws[(size_t)(g * 2 + 0) * 2048 + ((ks * 2 + mt_e) * 64 + lane) * 8];
            const short8 B = *(const short8*)&hws[(size_t)(g * 2 + 1) * 2048 + ((ks * 2 + mt_e) * 64 + lane) * 8];
            #pragma unroll
            for (int i = 0; i < 8; ++i) {
                const short v = f2bf(0.5f * (bf2f(F[i]) + bf2f(B[i])));
                if (ks == 0) A0[i] = v; else A1[i] = v;
            }
        }
        const floatx4 z4 = {0.f, 0.f, 0.f, 0.f};
        const floatx4 acc = MFMA16(A1, Bm1, MFMA16(A0, Bm0, z4));
        const float bmn = bm[n_col];
        #pragma unroll
        for (int r = 0; r < 4; ++r) {
            const int veh = mt_e * 16 + quad * 4 + r;
            const float sv = leakyf(acc[r] + bmn);
            const int n = index_div[g * NGRP + veh];
            full_enc[n * HH + n_col] = sv;
            fe[veh][n_col] = sv;
        }
    }

    // spatial B-frags
    short8 Bw00, Bw01, Bw10, Bw11;
    #pragma unroll
    for (int i = 0; i < 8; ++i) {
        Bw00[i] = f2bf(Ws2[(     quad * 8 + i) * 32 + cc]);
        Bw01[i] = f2bf(Ws2[(32 + quad * 8 + i) * 32 + cc]);
        Bw10[i] = f2bf(Ws2[(     quad * 8 + i) * 32 + 16 + cc]);
        Bw11[i] = f2bf(Ws2[(32 + quad * 8 + i) * 32 + 16 + cc]);
    }
    float bsq0[8], bsq1[8];
    #pragma unroll
    for (int i = 0; i < 8; ++i) {
        bsq0[i] = bs1[quad * 8 + i];
        bsq1[i] = bs1[32 + quad * 8 + i];
    }
    const float bs2c0 = bs2[cc], bs2c1 = bs2[16 + cc];
    __syncthreads();

    // spatial pairwise MLP: 4 waves x 8 j
    #pragma unroll 2
    for (int jj = 0; jj < 8; ++jj) {
        const int jrow = w * 8 + jj;
        float vj0[8], vj1[8];
        #pragma unroll
        for (int i = 0; i < 8; ++i) {
            vj0[i] = su[jrow][quad * 8 + i] - bsq0[i];
            vj1[i] = su[jrow][32 + quad * 8 + i] - bsq1[i];
        }
        float acc0 = 0.0f, acc1 = 0.0f;
        #pragma unroll
        for (int it = 0; it < 2; ++it) {
            const int irow = it * 16 + cc;
            const float4 p0 = *(const float4*)&su[irow][quad * 8];
            const float4 p1 = *(const float4*)&su[irow][quad * 8 + 4];
            const float4 p2 = *(const float4*)&su[irow][32 + quad * 8];
            const float4 p3 = *(const float4*)&su[irow][32 + quad * 8 + 4];
            short8 A0, A1;
            A0[0] = f2bf(leakyf(p0.x - vj0[0])); A0[1] = f2bf(leakyf(p0.y - vj0[1]));
            A0[2] = f2bf(leakyf(p0.z - vj0[2])); A0[3] = f2bf(leakyf(p0.w - vj0[3]));
            A0[4] = f2bf(leakyf(p1.x - vj0[4])); A0[5] = f2bf(leakyf(p1.y - vj0[5]));
            A0[6] = f2bf(leakyf(p1.z - vj0[6])); A0[7] = f2bf(leakyf(p1.w - vj0[7]));
            A1[0] = f2bf(leakyf(p2.x - vj1[0])); A1[1] = f2bf(leakyf(p2.y - vj1[1]));
            A1[2] = f2bf(leakyf(p2.z - vj1[2])); A1[3] = f2bf(leakyf(p2.w - vj1[3]));
            A1[4] = f2bf(leakyf(p3.x - vj1[4])); A1[5] = f2bf(leakyf(p3.y - vj1[5]));
            A1[6] = f2bf(leakyf(p3.z - vj1[6])); A1[7] = f2bf(leakyf(p3.w - vj1[7]));
            const floatx4 z4 = {0.f, 0.f, 0.f, 0.f};
            const floatx4 D0 = MFMA16(A1, Bw01, MFMA16(A0, Bw00, z4));
            const floatx4 D1 = MFMA16(A1, Bw11, MFMA16(A0, Bw10, z4));
            #pragma unroll
            for (int r = 0; r < 4; ++r) {
                acc0 += leakyf(D0[r] + bs2c0);
                acc1 += leakyf(D1[r] + bs2c1);
            }
        }
        acc0 += __shfl_xor(acc0, 16, 64); acc0 += __shfl_xor(acc0, 32, 64);
        acc1 += __shfl_xor(acc1, 16, 64); acc1 += __shfl_xor(acc1, 32, 64);
        const int n = index_div[g * NGRP + jrow];
        if (quad == 0) {
            const float pv = (acc0 - szero[cc]) * (1.0f / 31.0f);
            full_enc[n * HH + 32 + cc] = pv;
            fe[jrow][32 + cc] = pv;
        } else if (quad == 1) {
            const float pv = (acc1 - szero[16 + cc]) * (1.0f / 31.0f);
            full_enc[n * HH + 48 + cc] = pv;
            fe[jrow][48 + cc] = pv;
        }
    }
    __syncthreads();

    // head
    {
        const int veh = tid >> 3;
        const int p   = tid & 7;
        const int m0  = p * 2;
        float a0 = bo1[m0], a1 = bo1[m0 + 1];
        #pragma unroll
        for (int k = 0; k < HH; ++k) {
            const float f = fe[veh][k];
            const float2 wv = *(const float2*)&swo1[k * 16 + m0];
            a0 = fmaf(f, wv.x, a0);
            a1 = fmaf(f, wv.y, a1);
        }
        a0 = leakyf(a0); a1 = leakyf(a1);
        float l0 = fmaf(a0, Wo2[m0 * 3 + 0], a1 * Wo2[(m0 + 1) * 3 + 0]);
        float l1 = fmaf(a0, Wo2[m0 * 3 + 1], a1 * Wo2[(m0 + 1) * 3 + 1]);
        float l2 = fmaf(a0, Wo2[m0 * 3 + 2], a1 * Wo2[(m0 + 1) * 3 + 2]);
        #pragma unroll
        for (int off = 1; off < 8; off <<= 1) {
            l0 += __shfl_xor(l0, off, 64);
            l1 += __shfl_xor(l1, off, 64);
            l2 += __shfl_xor(l2, off, 64);
        }
        if (p == 0) {
            const int n = index_div[g * NGRP + veh];
            out[n * 3 + 0] = l0 + bo2[0];
            out[n * 3 + 1] = l1 + bo2[1];
            out[n * 3 + 2] = l2 + bo2[2];
        }
    }
}

// ---------------------------------------------------------------------------
extern "C" void kernel_launch(void* const* d_in, const int* in_sizes, int n_in,
                              void* d_out, int out_size, void* d_ws, size_t ws_size,
                              hipStream_t stream) {
    const float* scene     = (const float*)d_in[0];
    const int*   index_div = (const int*)d_in[4];
    const float* W_emb = (const float*)d_in[5];
    const float* b_emb = (const float*)d_in[6];
    const float* Wih_f = (const float*)d_in[7];
    const float* Whh_f = (const float*)d_in[8];
    const float* bih_f = (const float*)d_in[9];
    const float* bhh_f = (const float*)d_in[10];
    const float* Wih_b = (const float*)d_in[11];
    const float* Whh_b = (const float*)d_in[12];
    const float* bih_b = (const float*)d_in[13];
    const float* bhh_b = (const float*)d_in[14];
    const float* Wm  = (const float*)d_in[15];
    const float* bm  = (const float*)d_in[16];
    const float* Ws1 = (const float*)d_in[17];
    const float* bs1 = (const float*)d_in[18];
    const float* Ws2 = (const float*)d_in[19];
    const float* bs2 = (const float*)d_in[20];
    const float* Wo1 = (const float*)d_in[21];
    const float* bo1 = (const float*)d_in[22];
    const float* Wo2 = (const float*)d_in[23];
    const float* bo2 = (const float*)d_in[24];

    const int N = in_sizes[0] / (2 * TT);   // 32768
    const int G = in_sizes[4] / NGRP;       // 1024

    float* out      = (float*)d_out;
    float* full_enc = out + (size_t)N * CC;
    short* hws      = (short*)d_ws;         // 2G * 2048 shorts = 8 MB

    // grid = G: bx>>1 = group-pair (G/2), bx&1 = dir -> covers all groups/dirs
    gru_dir2_kernel<<<dim3(G), dim3(256), 0, stream>>>(
        scene, index_div, W_emb, b_emb, Wih_f, Whh_f, bih_f, bhh_f,
        Wih_b, Whh_b, bih_b, bhh_b, hws);

    tail_kernel<<<dim3(G), dim3(256), 0, stream>>>(
        scene, index_div, hws, Wm, bm, Ws1, bs1, Ws2, bs2,
        Wo1, bo1, Wo2, bo2, full_enc, out);
}